// Round 6
// baseline (314.481 us; speedup 1.0000x reference)
//
#include <hip/hip_runtime.h>

// AttentionSampling: out[b,s,:] = q[b,s,:] + sum_f dot(LN(q)[b,s,:], LN(k)[b,4s+f,:]) * LN(v)[b,4s+f,:]
// B=4, Sq=2048, Skv=8192, D=1024, fp32.
//
// R10: all five prior structures converge on ~20us per row-wave (~1 outstanding
// load avg). Root causes per attempt: compiler-inserted vmcnt(0) before C++ LDS
// reads of DMA destinations (R4/R5), RA load-sinking (R6), RA spill (R7), and
// C++ K-loads re-serialized (R9). Fix: remove the compiler from the loop
// entirely.
//   - ALL q/k/v traffic via global_load_lds (no dest VGPRs -> nothing to sink).
//   - ALL staged reads via inline-asm ds_read_b128 (invisible to the compiler's
//     waitcnt pass -> it cannot insert any vmcnt in the loop).
//   - ALL waits are mine: counted vmcnt, wave-private, never 0 mid-row.
// Per wave: 36KB LDS (Q,K0..K3,V slots), 8 rows, ring schedule:
//   waitQ/K01 -> consume -> prefetch next Q,K01 -> waitK23 -> consume ->
//   prefetch next K23 -> waitV -> stats -> DPP -> epilogue(V from LDS) ->
//   prefetch next V.
// vmcnt ledger (store-robust: counts EXCLUDE the 4 output stores, so they are
// safe under any store-retirement order; loads/DMA retire in-order, m135):
//   s2 (K1_i ready):  newer non-store = K23_i(8)+V_i(16)            = 24
//   s4 (K3_i ready):  newer non-store = V_i(16)+nextQK01(12)        = 28 (last row: 16)
//   s6 (V_i ready):   newer           = nextQK01(12)+nextK23(8)     = 20 (last row: 0)
// block=128 (2 waves, 72KB LDS), 512 blocks, 4 waves/CU. Each wave holds
// 12-36KB in flight continuously -> ~60-100KB/CU >> 14KB Little's-law need.

typedef float f32x4 __attribute__((ext_vector_type(4)));
typedef __attribute__((address_space(3))) float* lds_fp;

constexpr int D     = 1024;
constexpr int BLOCK = 128;
constexpr int WPB   = BLOCK / 64;   // 2 waves per block
constexpr int NRW   = 8;            // rows per wave
constexpr float EPS = 1e-5f;
constexpr int ROWF  = 9216;         // floats of LDS per wave (36 KB)
// slot offsets in floats within a wave's LDS row buffer
constexpr int SLQ = 0;              // q     : 1024
constexpr int SLK = 1024;           // k0..k3: 4096 (k_f at SLK + f*1024)
constexpr int SLV = 5120;           // v0..v3: 4096

#define GLOBAL_AS const __attribute__((address_space(1))) void*
#define LDS_AS __attribute__((address_space(3))) void*

template<int CTRL>
__device__ __forceinline__ float dpp_add(float x) {
    int xi = __builtin_bit_cast(int, x);
    int yi = __builtin_amdgcn_update_dpp(0, xi, CTRL, 0xF, 0xF, true);
    return x + __builtin_bit_cast(float, yi);
}

// Full wave64 sum on the VALU pipe; broadcast via readlane. No LDS, no barrier.
__device__ __forceinline__ float wave_sum(float x) {
    x = dpp_add<0x111>(x);   // row_shr:1
    x = dpp_add<0x112>(x);   // row_shr:2
    x = dpp_add<0x114>(x);   // row_shr:4
    x = dpp_add<0x118>(x);   // row_shr:8
    x = dpp_add<0x142>(x);   // row_bcast:15
    x = dpp_add<0x143>(x);   // row_bcast:31 -> lane 63 holds wave sum
    return __builtin_bit_cast(float, __builtin_amdgcn_readlane(__builtin_bit_cast(int, x), 63));
}

__device__ __forceinline__ f32x4 vadd(f32x4 a, f32x4 b) {
    f32x4 r;
#pragma unroll
    for (int j = 0; j < 4; j++) r[j] = a[j] + b[j];
    return r;
}
__device__ __forceinline__ f32x4 vmul(f32x4 a, f32x4 b) {
    f32x4 r;
#pragma unroll
    for (int j = 0; j < 4; j++) r[j] = a[j] * b[j];
    return r;
}
__device__ __forceinline__ f32x4 vfma(f32x4 a, f32x4 b, f32x4 c) {
    f32x4 r;
#pragma unroll
    for (int j = 0; j < 4; j++) r[j] = fmaf(a[j], b[j], c[j]);
    return r;
}
__device__ __forceinline__ f32x4 vfma_ss(f32x4 a, float s, float c) {
    f32x4 r;
#pragma unroll
    for (int j = 0; j < 4; j++) r[j] = fmaf(a[j], s, c);
    return r;
}
__device__ __forceinline__ f32x4 vfma_sv(float s, f32x4 b, f32x4 c) {
    f32x4 r;
#pragma unroll
    for (int j = 0; j < 4; j++) r[j] = fmaf(s, b[j], c[j]);
    return r;
}
__device__ __forceinline__ float hsum(f32x4 a) { return (a[0] + a[1]) + (a[2] + a[3]); }

// Counted vmcnt wait. "memory" clobber = compiler memory fence on both sides,
// so DMA-issue groups cannot hoist above their wait; sched_barrier pins VALU.
#define WAITV(N) do { asm volatile("s_waitcnt vmcnt(" #N ")" ::: "memory"); \
                      __builtin_amdgcn_sched_barrier(0); } while (0)

// Read 4 consecutive 1KB chunks (16B/lane each) from LDS, completion wait
// folded into the same asm so consumers can never run ahead of the data.
// Invisible to the compiler's waitcnt pass (plain VGPR in/out, no mem operand).
__device__ __forceinline__ void dsr4(lds_fp a, f32x4& d0, f32x4& d1, f32x4& d2, f32x4& d3) {
    asm volatile("ds_read_b128 %0, %4\n\t"
                 "ds_read_b128 %1, %4 offset:1024\n\t"
                 "ds_read_b128 %2, %4 offset:2048\n\t"
                 "ds_read_b128 %3, %4 offset:3072\n\t"
                 "s_waitcnt lgkmcnt(0)"
                 : "=&v"(d0), "=&v"(d1), "=&v"(d2), "=&v"(d3)
                 : "v"(a));
    __builtin_amdgcn_sched_barrier(0);
}

// Stage N 1KB chunks global->LDS, fire-and-forget, zero dest VGPRs.
template<int N>
__device__ __forceinline__ void stageN(const float* src, float* dst, int sl) {
#pragma unroll
    for (int c = 0; c < N; c++)
        __builtin_amdgcn_global_load_lds((GLOBAL_AS)(src + c * 256 + sl),
                                         (LDS_AS)(dst + c * 256), 16, 0, 0);
}

__global__ __launch_bounds__(BLOCK, 1) void attn_ds_kernel(
    const float* __restrict__ q,    // [rows, D]
    const float* __restrict__ k,    // [rows*4, D]
    const float* __restrict__ v,    // [rows*4, D]
    const float* __restrict__ lw,   // [D]
    const float* __restrict__ lb,   // [D]
    float* __restrict__ out,        // [rows, D]
    int rows)
{
    __shared__ float lds[WPB * ROWF];   // 72 KB: 36 KB per wave, wave-private

    const int  tid  = threadIdx.x;
    const int  lane = tid & 63;
    const int  wid  = tid >> 6;
    const int  sl   = lane * 4;                        // 16B slot within a chunk
    long r = ((long)blockIdx.x * WPB + wid) * NRW;     // first row of this wave
    if (r >= rows) return;                             // exact grid; no barriers anywhere

    float* Lbase = lds + wid * ROWF;                   // generic ptr for DMA dst
    lds_fp A     = (lds_fp)Lbase;                      // AS3 ptr for asm ds_read
    lds_fp Aq    = A + SLQ + sl;
    lds_fp Ak    = A + SLK + sl;
    lds_fp Av    = A + SLV + sl;

    // ---- w,b resident + invariant reductions (pre-loop: the compiler's own
    // vmcnt wait for these C++ loads lands HERE, before any DMA is issued) ----
    f32x4 wv[4], bv[4];
#pragma unroll
    for (int i = 0; i < 4; i++) {
        wv[i] = *(const f32x4*)(lw + i * 256 + sl);
        bv[i] = *(const f32x4*)(lb + i * 256 + sl);
    }
    f32x4 aw2 = {0.f,0.f,0.f,0.f}, awb = aw2, ab2 = aw2;
#pragma unroll
    for (int i = 0; i < 4; i++) {
        aw2 = vfma(wv[i], wv[i], aw2);
        awb = vfma(wv[i], bv[i], awb);
        ab2 = vfma(bv[i], bv[i], ab2);
    }
    const float Sw2 = wave_sum(hsum(aw2));
    const float Swb = wave_sum(hsum(awb));
    const float Sb2 = wave_sum(hsum(ab2));
    const float invD = 1.0f / (float)D;

    // ---- prologue: stage row r in ledger order Q,K0,K1 | K2,K3 | V ----
    stageN<4>(q + r * D,               Lbase + SLQ,        sl);
    stageN<4>(k + r * 4096,            Lbase + SLK,        sl);
    stageN<4>(k + r * 4096 + 1024,     Lbase + SLK + 1024, sl);
    stageN<4>(k + r * 4096 + 2048,     Lbase + SLK + 2048, sl);
    stageN<4>(k + r * 4096 + 3072,     Lbase + SLK + 3072, sl);
    stageN<16>(v + r * 4096,           Lbase + SLV,        sl);

#pragma unroll 1
    for (int i = 0; i < NRW; i++, r++) {
        const bool last = (i == NRW - 1);
        const long rn = r + 1;

        // ---- s2: Q,K0,K1 ready (newer non-store: K23=8 + V=16 = 24) ----
        WAITV(24);
        f32x4 qv0, qv1, qv2, qv3;
        dsr4(Aq, qv0, qv1, qv2, qv3);
        f32x4 qw[4];
        qw[0] = vmul(qv0, wv[0]); qw[1] = vmul(qv1, wv[1]);
        qw[2] = vmul(qv2, wv[2]); qw[3] = vmul(qv3, wv[3]);
        float pSq, pSqq, pSqw2, pSqwb;
        {
            f32x4 a0 = vadd(vadd(qv0, qv1), vadd(qv2, qv3));
            f32x4 a1 = vfma(qv0, qv0, vfma(qv1, qv1, vfma(qv2, qv2, vmul(qv3, qv3))));
            f32x4 a2 = vfma(qw[0], wv[0], vfma(qw[1], wv[1], vfma(qw[2], wv[2], vmul(qw[3], wv[3]))));
            f32x4 a3 = vfma(qw[0], bv[0], vfma(qw[1], bv[1], vfma(qw[2], bv[2], vmul(qw[3], bv[3]))));
            pSq = hsum(a0); pSqq = hsum(a1); pSqw2 = hsum(a2); pSqwb = hsum(a3);
        }
        float pSk[4], pSkk[4], pSkw2[4], pSkwb[4], pA[4];
        f32x4 c0, c1, c2, c3;
#define PROCK(f) { \
        f32x4 s = {0.f,0.f,0.f,0.f}, ss = s, sw2a = s, swba = s, sA = s; \
        s = vadd(vadd(c0, c1), vadd(c2, c3)); \
        ss = vfma(c0, c0, vfma(c1, c1, vfma(c2, c2, vmul(c3, c3)))); \
        { f32x4 t = vmul(c0, wv[0]); sw2a = vfma(t, wv[0], sw2a); swba = vfma(t, bv[0], swba); sA = vfma(t, qw[0], sA); } \
        { f32x4 t = vmul(c1, wv[1]); sw2a = vfma(t, wv[1], sw2a); swba = vfma(t, bv[1], swba); sA = vfma(t, qw[1], sA); } \
        { f32x4 t = vmul(c2, wv[2]); sw2a = vfma(t, wv[2], sw2a); swba = vfma(t, bv[2], swba); sA = vfma(t, qw[2], sA); } \
        { f32x4 t = vmul(c3, wv[3]); sw2a = vfma(t, wv[3], sw2a); swba = vfma(t, bv[3], swba); sA = vfma(t, qw[3], sA); } \
        pSk[f] = hsum(s); pSkk[f] = hsum(ss); \
        pSkw2[f] = hsum(sw2a); pSkwb[f] = hsum(swba); pA[f] = hsum(sA); }

        dsr4(Ak,        c0, c1, c2, c3); PROCK(0);
        dsr4(Ak + 1024, c0, c1, c2, c3); PROCK(1);

        // ---- s3: prefetch next Q,K0,K1 (12 ops) ----
        if (!last) {
            stageN<4>(q + rn * D,           Lbase + SLQ,        sl);
            stageN<4>(k + rn * 4096,        Lbase + SLK,        sl);
            stageN<4>(k + rn * 4096 + 1024, Lbase + SLK + 1024, sl);
        }

        // ---- s4: K2,K3 ready (newer non-store: V=16 + nextQK01=12 = 28; last: 16) ----
        if (last) WAITV(16); else WAITV(28);
        dsr4(Ak + 2048, c0, c1, c2, c3); PROCK(2);
        dsr4(Ak + 3072, c0, c1, c2, c3); PROCK(3);
#undef PROCK

        // ---- s5: prefetch next K2,K3 (8 ops) ----
        if (!last) {
            stageN<4>(k + rn * 4096 + 2048, Lbase + SLK + 2048, sl);
            stageN<4>(k + rn * 4096 + 3072, Lbase + SLK + 3072, sl);
        }

        // ---- s6: V ready (newer: nextQK01=12 + nextK23=8 = 20; last: 0) ----
        if (last) WAITV(0); else WAITV(20);
        float pSv[4], pSvv[4];
#pragma unroll
        for (int f = 0; f < 4; f++) {
            f32x4 e0, e1, e2, e3;
            dsr4(Av + f * 1024, e0, e1, e2, e3);
            f32x4 s  = vadd(vadd(e0, e1), vadd(e2, e3));
            f32x4 ss = vfma(e0, e0, vfma(e1, e1, vfma(e2, e2, vmul(e3, e3))));
            pSv[f] = hsum(s); pSvv[f] = hsum(ss);
        }

        // ---- s7: one DPP reduction round (32 sums) + scalar stats ----
        const float Sq   = wave_sum(pSq);
        const float Sqq  = wave_sum(pSqq);
        const float Sqw2 = wave_sum(pSqw2);
        const float Sqwb = wave_sum(pSqwb);
        float Sk[4], Skk[4], Skw2[4], Skwb[4], Ax[4], Sv[4], Svv[4];
#pragma unroll
        for (int f = 0; f < 4; f++) {
            Sk[f]   = wave_sum(pSk[f]);
            Skk[f]  = wave_sum(pSkk[f]);
            Skw2[f] = wave_sum(pSkw2[f]);
            Skwb[f] = wave_sum(pSkwb[f]);
            Ax[f]   = wave_sum(pA[f]);
            Sv[f]   = wave_sum(pSv[f]);
            Svv[f]  = wave_sum(pSvv[f]);
        }
        const float mu_q = Sq * invD;
        const float rs_q = rsqrtf(fmaf(-mu_q, mu_q, Sqq * invD) + EPS);
        const float qlin = rs_q * (Sqwb - mu_q * Swb);
        float dp[4], rs_v[4], cv[4];
#pragma unroll
        for (int f = 0; f < 4; f++) {
            const float mu_k = Sk[f] * invD;
            const float rs_k = rsqrtf(fmaf(-mu_k, mu_k, Skk[f] * invD) + EPS);
            const float mu_v = Sv[f] * invD;
            const float rv   = rsqrtf(fmaf(-mu_v, mu_v, Svv[f] * invD) + EPS);
            const float cross = Ax[f] - mu_k * Sqw2 - mu_q * Skw2[f] + mu_q * mu_k * Sw2;
            dp[f] = rs_q * rs_k * cross + qlin + rs_k * (Skwb[f] - mu_k * Swb) + Sb2;
            rs_v[f] = rv;
            cv[f]   = -mu_v * rv;
        }

        // ---- s8: epilogue, V re-read from LDS; out = q + sum_f dp_f*LN(v_f) ----
        f32x4 o0 = qv0, o1 = qv1, o2 = qv2, o3 = qv3;
#pragma unroll
        for (int f = 0; f < 4; f++) {
            f32x4 e0, e1, e2, e3;
            dsr4(Av + f * 1024, e0, e1, e2, e3);
            o0 = vfma_sv(dp[f], vfma(vfma_ss(e0, rs_v[f], cv[f]), wv[0], bv[0]), o0);
            o1 = vfma_sv(dp[f], vfma(vfma_ss(e1, rs_v[f], cv[f]), wv[1], bv[1]), o1);
            o2 = vfma_sv(dp[f], vfma(vfma_ss(e2, rs_v[f], cv[f]), wv[2], bv[2]), o2);
            o3 = vfma_sv(dp[f], vfma(vfma_ss(e3, rs_v[f], cv[f]), wv[3], bv[3]), o3);
        }
        float* op = out + r * (long)D + sl;
        *(f32x4*)(op)       = o0;
        *(f32x4*)(op + 256) = o1;
        *(f32x4*)(op + 512) = o2;
        *(f32x4*)(op + 768) = o3;

        // ---- s9: prefetch next V (16 ops; V_i fully consumed above) ----
        if (!last) stageN<16>(v + rn * 4096, Lbase + SLV, sl);
    }
}

extern "C" void kernel_launch(void* const* d_in, const int* in_sizes, int n_in,
                              void* d_out, int out_size, void* d_ws, size_t ws_size,
                              hipStream_t stream) {
    const float* q  = (const float*)d_in[0];
    const float* k  = (const float*)d_in[1];
    const float* v  = (const float*)d_in[2];
    const float* lw = (const float*)d_in[3];
    const float* lb = (const float*)d_in[4];
    float* out = (float*)d_out;

    const int rows = in_sizes[0] / D;                       // B*Sq = 8192
    const int grid = (rows + WPB * NRW - 1) / (WPB * NRW);  // 512 blocks
    attn_ds_kernel<<<dim3(grid), dim3(BLOCK), 0, stream>>>(q, k, v, lw, lb, out, rows);
}